// Round 9
// baseline (99.572 us; speedup 1.0000x reference)
//
#include <hip/hip_runtime.h>
#include <stdint.h>

// InterGate: B=1, C=192, H=W=96.  Flash-attention formulation:
//   Q = (latent*w4)^T, K = refined^T, V = (latent*w4)^T   (all [9216, 192])
//   out = refined*w5 + (softmax(Q K^T) V)^T
// Round-9: r8's layout/math + intra-wave software pipelining.
// r8 counters: LDS 50% + MFMA 34% + VALU 22% ~= serialized (sum 106%).
// Cause: per-wave program order QK->softmax->PV, each MFMA fed by a fresh
// ds_read -> a wave never overlaps pipes.  Fix: iteration kt computes
// softmax(kt-1) then QK(kt) and PV(kt-1) MFMAs interleaved 1:1 (S_prev in
// regs) -> each iteration presents LDS + VALU + 24 back-to-back MFMAs as
// one dependence-free region.
//   * K/V separate triple buffers (6 x 12KB = 72KB, 2 blocks/CU)
//   * V staging lags K by one iter -> every buffer rewrite barrier-protected
//   * counted vmcnt(6) steady, vmcnt(3) last iter, vmcnt(0)+barrier epilogue
//   * f16 single-term swapped QK, no-max softmax P=2^(S-M0L), permuted-V
//     rows (P B-frag = cvt_pk words, zero cross-lane moves)

#define NQ 9216
#define NC 192
#define FR 1769472      // 9216*192 elements per fragment array
#define LOG2E 1.4426950408889634f
#define M0L 36.06737602f   // 25 * log2(e)

typedef short    bfrag  __attribute__((ext_vector_type(8)));   // 8 bf16
typedef _Float16 hfrag  __attribute__((ext_vector_type(8)));   // 8 f16
typedef short    sfrag4 __attribute__((ext_vector_type(4)));   // 4 bf16 (8B)
typedef float    facc16 __attribute__((ext_vector_type(16)));  // 32x32 accum

__device__ __forceinline__ short f2bf(float x) {
    uint32_t u = __builtin_bit_cast(uint32_t, x);
    u = (u + 0x7fffu + ((u >> 16) & 1u)) >> 16;
    return (short)u;
}
__device__ __forceinline__ float bf2f(short s) {
    uint32_t u = ((uint32_t)(uint16_t)s) << 16;
    return __builtin_bit_cast(float, u);
}
__device__ __forceinline__ int cvtpk_bf16(float lo, float hi) {
    int r;
    asm("v_cvt_pk_bf16_f32 %0, %1, %2" : "=v"(r) : "v"(lo), "v"(hi));
    return r;
}
__device__ __forceinline__ float exp2_raw(float x) {   // 2^x via v_exp_f32
    float r;
    asm("v_exp_f32 %0, %1" : "=v"(r) : "v"(x));
    return r;
}
__device__ __forceinline__ bfrag words_to_frag(int w0, int w1, int w2, int w3) {
    union { int i[4]; bfrag f; } u;
    u.i[0] = w0; u.i[1] = w1; u.i[2] = w2; u.i[3] = w3;
    return u.f;
}
__device__ __forceinline__ void gload_lds16(const void* g, void* l) {
    __builtin_amdgcn_global_load_lds(
        (__attribute__((address_space(1))) const void*)(uintptr_t)g,
        (__attribute__((address_space(3))) void*)(uint32_t)(uintptr_t)l,
        16, 0, 0);
}

// ---------------------------------------------------------------------------
// Prep: fragment-ordered arrays for 32x32x16 (l32=lane&31, h=lane>>5).
// Qf (f16, B-frag, pre-scaled by log2e):
//   [qw(288)][t(12)][lane][i8] = log2e * Q[qw*32+l32][t*16+h*8+i]
// KV per 32-key group g (12288 shorts = 24KB), 288 groups:
//  [0]    K (f16, A-frag): [t(12)][lane][i8] = K[g*32+l32][t*16+h*8+i]
//  [6144] V (bf16, A-frag of V^T, PERMUTED key rows matching S' C/D order):
//         [T(2)][cb(6)][lane][i8] = V[g*32+T*16+(i&3)+8*(i>>2)+4*h][cb*32+l32]
// ---------------------------------------------------------------------------
__global__ __launch_bounds__(256) void InterGate_prep(
    const float* __restrict__ latent, const float* __restrict__ refined,
    const float* __restrict__ w4,
    short* __restrict__ Qf, short* __restrict__ KV)
{
    const int wid  = blockIdx.x * 4 + (threadIdx.x >> 6);
    const int lane = threadIdx.x & 63;
    const int l32  = lane & 31, h = lane >> 5;

    if (wid < 3456) {                       // Q fragments (latent*w4*log2e), f16
        const int qw = wid / 12, t = wid % 12;
        const int q  = qw * 32 + l32;
        const int c0 = t * 16 + h * 8;
        hfrag hv;
        #pragma unroll
        for (int i = 0; i < 8; i++) {
            size_t idx = (size_t)(c0 + i) * NQ + q;
            hv[i] = (_Float16)(latent[idx] * w4[idx] * LOG2E);
        }
        *(hfrag*)(void*)(Qf + ((size_t)wid * 64 + lane) * 8) = hv;
    } else if (wid < 6912) {                // K fragments (refined), f16
        const int u = wid - 3456;           // u = g*12 + t
        const int g = u / 12, t = u % 12;
        const int key = g * 32 + l32;
        const int c0  = t * 16 + h * 8;
        hfrag hv;
        #pragma unroll
        for (int i = 0; i < 8; i++) {
            size_t idx = (size_t)(c0 + i) * NQ + key;
            hv[i] = (_Float16)refined[idx];
        }
        *(hfrag*)(void*)(KV + (size_t)g * 12288 + ((t * 64 + lane) * 8)) = hv;
    } else {                                // V fragments (latent*w4), bf16, permuted
        const int u = wid - 6912;           // u = g*12 + T*6 + cb
        const int g = u / 12, r = u % 12;
        const int T = r / 6, cb = r % 6;
        const int c  = cb * 32 + l32;
        const int k0 = g * 32 + T * 16 + 4 * h;
        bfrag bv;
        #pragma unroll
        for (int i = 0; i < 8; i++) {
            const int row = k0 + (i & 3) + 8 * (i >> 2);
            size_t idx = (size_t)c * NQ + row;
            bv[i] = f2bf(latent[idx] * w4[idx]);
        }
        *(bfrag*)(void*)(KV + (size_t)g * 12288 + 6144 + ((T * 6 + cb) * 64 + lane) * 8) = bv;
    }
}

// ---------------------------------------------------------------------------
// Flash: grid (72 q-tiles of 128, KS key-splits in 32-key units), 4 waves
// x 32 q, 72KB LDS/block -> 2 blocks/CU.  K/V triple-buffered separately;
// software-pipelined iteration: softmax(kt-1) + QK(kt)/PV(kt-1) interleaved.
// ---------------------------------------------------------------------------
__device__ __forceinline__ void stage12(const short* KVsrc, char* dstb,
                                        int w, int lane) {
    // 12KB buffer, 12 x 1KB chunks, 3 per wave
    const char* src = (const char*)KVsrc + w * 3072 + lane * 16;
    char* dst = dstb + w * 3072;            // wave-uniform base (+lane*16 HW)
    #pragma unroll
    for (int j = 0; j < 3; j++) gload_lds16(src + j * 1024, dst + j * 1024);
}

__global__ __launch_bounds__(256, 2) void InterGate_flash(
    const short* __restrict__ Qf, const short* __restrict__ KV,
    short* __restrict__ Opart, float* __restrict__ l_ws, int KS)
{
    __shared__ __align__(16) short kbufs[3][6144];   // 3 x 12KB K (f16)
    __shared__ __align__(16) short vbufs[3][6144];   // 3 x 12KB V (bf16)

    const int tid  = threadIdx.x;
    const int lane = tid & 63, w = tid >> 6;
    const int l32  = lane & 31, h = lane >> 5;
    const int qt   = blockIdx.x, ks = blockIdx.y;

    // key range in 32-key units (288 total)
    const int base = 288 / KS, rem = 288 % KS;
    const int start = ks * base + (ks < rem ? ks : rem);
    const int cnt   = base + (ks < rem ? 1 : 0);

    // Q B-frags in registers (48 VGPR)
    const int qw = qt * 4 + w;
    hfrag qf[12];
    #pragma unroll
    for (int t = 0; t < 12; t++)
        qf[t] = *(const hfrag*)(const void*)(Qf + (((size_t)qw * 12 + t) * 64 + lane) * 8);

    facc16 O[6];
    #pragma unroll
    for (int cb = 0; cb < 6; cb++)
        #pragma unroll
        for (int j = 0; j < 16; j++) O[cb][j] = 0.f;
    float lsum = 0.f;

    // prologue staging: K(0), V(0), K(1)   (9 loads/wave in flight)
    stage12(KV + (size_t)start * 12288,        (char*)&kbufs[0][0], w, lane);
    stage12(KV + (size_t)start * 12288 + 6144, (char*)&vbufs[0][0], w, lane);
    if (cnt > 1)
        stage12(KV + (size_t)(start + 1) * 12288, (char*)&kbufs[1][0], w, lane);

    facc16 Sp;            // S of previous tile (softmax deferred one iter)
    #pragma unroll
    for (int j = 0; j < 16; j++) Sp[j] = 0.f;

    for (int kt = 0; kt < cnt; kt++) {
        // ---- tile boundary: counted wait, then barrier ----
        if (kt + 1 < cnt) { asm volatile("s_waitcnt vmcnt(6)" ::: "memory"); }
        else              { asm volatile("s_waitcnt vmcnt(3)" ::: "memory"); }
        __builtin_amdgcn_s_barrier();

        // issue stages (buffers being rewritten: readers passed prev barrier)
        if (kt + 2 < cnt)
            stage12(KV + (size_t)(start + kt + 2) * 12288,
                    (char*)&kbufs[(kt + 2) % 3][0], w, lane);
        if (kt + 1 < cnt)
            stage12(KV + (size_t)(start + kt + 1) * 12288 + 6144,
                    (char*)&vbufs[(kt + 1) % 3][0], w, lane);

        const short* kb = &kbufs[kt % 3][0];

        if (kt == 0) {
            // peeled: QK only
            facc16 S;
            #pragma unroll
            for (int j = 0; j < 16; j++) S[j] = 0.f;
            __builtin_amdgcn_s_setprio(1);
            #pragma unroll
            for (int t = 0; t < 12; t++) {
                hfrag kf = *(const hfrag*)(const void*)(kb + t * 512 + lane * 8);
                S = __builtin_amdgcn_mfma_f32_32x32x16_f16(kf, qf[t], S, 0, 0, 0);
            }
            __builtin_amdgcn_s_setprio(0);
            Sp = S;
            continue;
        }

        // ---- softmax of tile kt-1 (VALU/TRANS; independent of this tile) ----
        float p[16];
        #pragma unroll
        for (int j = 0; j < 16; j++) p[j] = exp2_raw(Sp[j] - M0L);
        lsum += (((p[0]+p[1])+(p[2]+p[3]))+((p[4]+p[5])+(p[6]+p[7])))
              + (((p[8]+p[9])+(p[10]+p[11]))+((p[12]+p[13])+(p[14]+p[15])));
        int cp[8];
        #pragma unroll
        for (int a = 0; a < 8; a++) cp[a] = cvtpk_bf16(p[2 * a], p[2 * a + 1]);
        bfrag pf0 = words_to_frag(cp[0], cp[1], cp[2], cp[3]);
        bfrag pf1 = words_to_frag(cp[4], cp[5], cp[6], cp[7]);

        // ---- QK(kt) and PV(kt-1) interleaved 1:1 (24 MFMAs, one region) ----
        const short* vb = &vbufs[(kt - 1) % 3][0];
        facc16 S;
        #pragma unroll
        for (int j = 0; j < 16; j++) S[j] = 0.f;
        __builtin_amdgcn_s_setprio(1);
        #pragma unroll
        for (int t = 0; t < 12; t++) {
            hfrag kf = *(const hfrag*)(const void*)(kb + t * 512 + lane * 8);
            S = __builtin_amdgcn_mfma_f32_32x32x16_f16(kf, qf[t], S, 0, 0, 0);
            bfrag vf = *(const bfrag*)(const void*)(vb + t * 512 + lane * 8);
            O[t % 6] = __builtin_amdgcn_mfma_f32_32x32x16_bf16(
                vf, (t < 6 ? pf0 : pf1), O[t % 6], 0, 0, 0);
        }
        __builtin_amdgcn_s_setprio(0);
        Sp = S;
    }

    // ---- epilogue: softmax + PV of the final tile ----
    asm volatile("s_waitcnt vmcnt(0)" ::: "memory");
    __builtin_amdgcn_s_barrier();
    {
        float p[16];
        #pragma unroll
        for (int j = 0; j < 16; j++) p[j] = exp2_raw(Sp[j] - M0L);
        lsum += (((p[0]+p[1])+(p[2]+p[3]))+((p[4]+p[5])+(p[6]+p[7])))
              + (((p[8]+p[9])+(p[10]+p[11]))+((p[12]+p[13])+(p[14]+p[15])));
        int cp[8];
        #pragma unroll
        for (int a = 0; a < 8; a++) cp[a] = cvtpk_bf16(p[2 * a], p[2 * a + 1]);
        bfrag pf0 = words_to_frag(cp[0], cp[1], cp[2], cp[3]);
        bfrag pf1 = words_to_frag(cp[4], cp[5], cp[6], cp[7]);
        const short* vb = &vbufs[(cnt - 1) % 3][0];
        __builtin_amdgcn_s_setprio(1);
        #pragma unroll
        for (int t = 0; t < 12; t++) {
            bfrag vf = *(const bfrag*)(const void*)(vb + t * 512 + lane * 8);
            O[t % 6] = __builtin_amdgcn_mfma_f32_32x32x16_bf16(
                vf, (t < 6 ? pf0 : pf1), O[t % 6], 0, 0, 0);
        }
        __builtin_amdgcn_s_setprio(0);
    }

    // ---- epilogue: Opart[ks][q][c] (bf16, unnormalized) + l per query ----
    const int q0 = qt * 128 + w * 32 + l32;
    short* row = Opart + ((size_t)ks * NQ + q0) * NC;
    #pragma unroll
    for (int cb = 0; cb < 6; cb++) {
        #pragma unroll
        for (int g = 0; g < 4; g++) {
            const int c0 = cb * 32 + 8 * g + 4 * h;
            sfrag4 s4;
            #pragma unroll
            for (int r = 0; r < 4; r++) s4[r] = f2bf(O[cb][4 * g + r]);
            *(sfrag4*)(void*)(row + c0) = s4;
        }
    }
    float lt = lsum + __shfl_xor(lsum, 32);
    if (h == 0) l_ws[(size_t)ks * NQ + q0] = lt;
}

// ---------------------------------------------------------------------------
// Combine: sum KS partials (common scale), normalize, transpose via LDS,
// fused epilogue out = refined*w5 + ctx.  288 blocks x 32 queries.
// ---------------------------------------------------------------------------
__global__ __launch_bounds__(256) void InterGate_combine(
    const short* __restrict__ Opart, const float* __restrict__ l_ws,
    const float* __restrict__ refined, const float* __restrict__ w5,
    float* __restrict__ out, int KS)
{
    __shared__ float ctx[32][193];
    __shared__ float sInv[32];
    const int qt = blockIdx.x, tid = threadIdx.x;

    if (tid < 32) {
        const int q = qt * 32 + tid;
        float L = 0.f;
        for (int ks = 0; ks < KS; ks++) L += l_ws[(size_t)ks * NQ + q];
        sInv[tid] = 1.f / L;
    }
    __syncthreads();

    for (int u = tid; u < 768; u += 256) {
        const int ql = u / 24, c0 = (u % 24) * 8;
        float acc[8] = {0.f, 0.f, 0.f, 0.f, 0.f, 0.f, 0.f, 0.f};
        for (int ks = 0; ks < KS; ks++) {
            bfrag pk = *(const bfrag*)(const void*)&Opart[((size_t)ks * NQ + qt * 32 + ql) * NC + c0];
            #pragma unroll
            for (int j = 0; j < 8; j++) acc[j] += bf2f(pk[j]);
        }
        const float inv = sInv[ql];
        #pragma unroll
        for (int j = 0; j < 8; j++) ctx[ql][c0 + j] = acc[j] * inv;
    }
    __syncthreads();

    for (int u = tid; u < 6144; u += 256) {
        const int c = u / 32, qx = u % 32;
        size_t o = (size_t)c * NQ + qt * 32 + qx;
        out[o] = refined[o] * w5[o] + ctx[qx][c];
    }
}

// ---------------------------------------------------------------------------
extern "C" void kernel_launch(void* const* d_in, const int* in_sizes, int n_in,
                              void* d_out, int out_size, void* d_ws, size_t ws_size,
                              hipStream_t stream)
{
    (void)in_sizes; (void)n_in; (void)out_size;
    const float* latent  = (const float*)d_in[0];
    const float* refined = (const float*)d_in[1];
    const float* w4      = (const float*)d_in[2];
    const float* w5      = (const float*)d_in[3];
    float* out = (float*)d_out;

    short* Qf = (short*)d_ws;
    short* KV = Qf + FR;                     // 2*FR shorts (K|V per 32-key group)
    const size_t basebytes = (size_t)3 * FR * 2;

    // KS=7 -> grid 504 (~2 blocks/CU, 72KB LDS each); fallbacks if ws small
    const int opts[4] = {7, 4, 2, 1};
    int KS = 0;
    for (int i = 0; i < 4; i++) {
        size_t need = basebytes + (size_t)opts[i] * ((size_t)NQ * NC * 2 + (size_t)NQ * 4);
        if (need <= ws_size) { KS = opts[i]; break; }
    }
    if (KS == 0) return;

    short* Opart = (short*)((char*)d_ws + basebytes);
    float* l_ws  = (float*)((char*)d_ws + basebytes + (size_t)KS * NQ * NC * 2);

    InterGate_prep<<<2592, 256, 0, stream>>>(latent, refined, w4, Qf, KV);
    dim3 fg(72, KS);
    InterGate_flash<<<fg, 256, 0, stream>>>(Qf, KV, Opart, l_ws, KS);
    InterGate_combine<<<288, 256, 0, stream>>>(Opart, l_ws, refined, w5, out, KS);
}

// Round 10
// 98.060 us; speedup vs baseline: 1.0154x; 1.0154x over previous
//
#include <hip/hip_runtime.h>
#include <stdint.h>

// InterGate: B=1, C=192, H=W=96.  Flash-attention formulation:
//   Q = (latent*w4)^T, K = refined^T, V = (latent*w4)^T   (all [9216, 192])
//   out = refined*w5 + (softmax(Q K^T) V)^T
// Round-10: r8's shape (4 waves x 32q, 32-key tiles, 3x24KB bufs, counted
// vmcnt, 2 blocks/CU) + EXPLICIT LDS->reg software pipelining inside the
// tile.  r7-r9 all landed at 74-78us because every MFMA consumed a
// just-issued ds_read -> compiler batch-reads, lgkmcnt-drains, then MFMA
// bursts: LDS pipe (51%) and MFMA pipe (34%) alternate instead of overlap.
// Here fragments are loaded into named locals 4-8 MFMAs ahead, giving the
// compiler counted lgkmcnt waits: 12-cyc LDS reads hide in 32-cyc MFMAs.
//   * f16 single-term swapped QK, no-max softmax P=2^(S-M0L), permuted-V
//     rows (P B-frag = cvt_pk words, zero cross-lane moves)  [validated]
//   * counted s_waitcnt vmcnt(6) + raw s_barrier, triple buffer, setprio

#define NQ 9216
#define NC 192
#define FR 1769472      // 9216*192 elements per fragment array
#define LOG2E 1.4426950408889634f
#define M0L 36.06737602f   // 25 * log2(e)

typedef short    bfrag  __attribute__((ext_vector_type(8)));   // 8 bf16
typedef _Float16 hfrag  __attribute__((ext_vector_type(8)));   // 8 f16
typedef short    sfrag4 __attribute__((ext_vector_type(4)));   // 4 bf16 (8B)
typedef float    facc16 __attribute__((ext_vector_type(16)));  // 32x32 accum
typedef int      ifrag4 __attribute__((ext_vector_type(4)));

__device__ __forceinline__ short f2bf(float x) {
    uint32_t u = __builtin_bit_cast(uint32_t, x);
    u = (u + 0x7fffu + ((u >> 16) & 1u)) >> 16;
    return (short)u;
}
__device__ __forceinline__ float bf2f(short s) {
    uint32_t u = ((uint32_t)(uint16_t)s) << 16;
    return __builtin_bit_cast(float, u);
}
__device__ __forceinline__ int cvtpk_bf16(float lo, float hi) {
    int r;
    asm("v_cvt_pk_bf16_f32 %0, %1, %2" : "=v"(r) : "v"(lo), "v"(hi));
    return r;
}
__device__ __forceinline__ float exp2_raw(float x) {   // 2^x via v_exp_f32
    float r;
    asm("v_exp_f32 %0, %1" : "=v"(r) : "v"(x));
    return r;
}
__device__ __forceinline__ void gload_lds16(const void* g, void* l) {
    __builtin_amdgcn_global_load_lds(
        (__attribute__((address_space(1))) const void*)(uintptr_t)g,
        (__attribute__((address_space(3))) void*)(uint32_t)(uintptr_t)l,
        16, 0, 0);
}

// ---------------------------------------------------------------------------
// Prep: fragment-ordered arrays for 32x32x16 (l32=lane&31, h=lane>>5).
// Qf (f16, B-frag, pre-scaled by log2e):
//   [qw(288)][t(12)][lane][i8] = log2e * Q[qw*32+l32][t*16+h*8+i]
// KV per 32-key group g (12288 shorts = 24KB), 288 groups:
//  [0]    K (f16, A-frag): [t(12)][lane][i8] = K[g*32+l32][t*16+h*8+i]
//  [6144] V (bf16, A-frag of V^T, PERMUTED key rows matching S' C/D order):
//         [T(2)][cb(6)][lane][i8] = V[g*32+T*16+(i&3)+8*(i>>2)+4*h][cb*32+l32]
// ---------------------------------------------------------------------------
__global__ __launch_bounds__(256) void InterGate_prep(
    const float* __restrict__ latent, const float* __restrict__ refined,
    const float* __restrict__ w4,
    short* __restrict__ Qf, short* __restrict__ KV)
{
    const int wid  = blockIdx.x * 4 + (threadIdx.x >> 6);
    const int lane = threadIdx.x & 63;
    const int l32  = lane & 31, h = lane >> 5;

    if (wid < 3456) {                       // Q fragments (latent*w4*log2e), f16
        const int qw = wid / 12, t = wid % 12;
        const int q  = qw * 32 + l32;
        const int c0 = t * 16 + h * 8;
        hfrag hv;
        #pragma unroll
        for (int i = 0; i < 8; i++) {
            size_t idx = (size_t)(c0 + i) * NQ + q;
            hv[i] = (_Float16)(latent[idx] * w4[idx] * LOG2E);
        }
        *(hfrag*)(void*)(Qf + ((size_t)wid * 64 + lane) * 8) = hv;
    } else if (wid < 6912) {                // K fragments (refined), f16
        const int u = wid - 3456;           // u = g*12 + t
        const int g = u / 12, t = u % 12;
        const int key = g * 32 + l32;
        const int c0  = t * 16 + h * 8;
        hfrag hv;
        #pragma unroll
        for (int i = 0; i < 8; i++) {
            size_t idx = (size_t)(c0 + i) * NQ + key;
            hv[i] = (_Float16)refined[idx];
        }
        *(hfrag*)(void*)(KV + (size_t)g * 12288 + ((t * 64 + lane) * 8)) = hv;
    } else {                                // V fragments (latent*w4), bf16, permuted
        const int u = wid - 6912;           // u = g*12 + T*6 + cb
        const int g = u / 12, r = u % 12;
        const int T = r / 6, cb = r % 6;
        const int c  = cb * 32 + l32;
        const int k0 = g * 32 + T * 16 + 4 * h;
        bfrag bv;
        #pragma unroll
        for (int i = 0; i < 8; i++) {
            const int row = k0 + (i & 3) + 8 * (i >> 2);
            size_t idx = (size_t)c * NQ + row;
            bv[i] = f2bf(latent[idx] * w4[idx]);
        }
        *(bfrag*)(void*)(KV + (size_t)g * 12288 + 6144 + ((T * 6 + cb) * 64 + lane) * 8) = bv;
    }
}

// ---------------------------------------------------------------------------
// Flash: grid (72 q-tiles of 128, KS key-splits in 32-key units), 4 waves
// x 32 q, 72KB LDS/block -> 2 blocks/CU.  Triple-buffered 24KB K|V tiles,
// staged 2 ahead; inside each tile the LDS->reg loads run 4-8 MFMAs ahead.
// ---------------------------------------------------------------------------
__device__ __forceinline__ void stage24(const short* KVsrc, char* dstb,
                                        int w, int lane) {
    const char* src = (const char*)KVsrc + w * 6144 + lane * 16;
    char* dst = dstb + w * 6144;            // wave-uniform base (+lane*16 HW)
    #pragma unroll
    for (int j = 0; j < 6; j++) gload_lds16(src + j * 1024, dst + j * 1024);
}

#define KLD(n)  *(const hfrag*)(const void*)(kb + (n) * 512 + lane * 8)
#define VLD(n)  *(const bfrag*)(const void*)(kb + 6144 + (n) * 512 + lane * 8)
#define QKM(kf, t)  S = __builtin_amdgcn_mfma_f32_32x32x16_f16((kf), qf[t], S, 0, 0, 0)
#define PVM(vf, cb, pf) O[cb] = __builtin_amdgcn_mfma_f32_32x32x16_bf16((vf), (pf), O[cb], 0, 0, 0)

__global__ __launch_bounds__(256, 2) void InterGate_flash(
    const short* __restrict__ Qf, const short* __restrict__ KV,
    short* __restrict__ Opart, float* __restrict__ l_ws, int KS)
{
    __shared__ __align__(16) short kv[3][12288];   // 3 x 24KB: K(f16) | V(bf16)

    const int tid  = threadIdx.x;
    const int lane = tid & 63, w = tid >> 6;
    const int l32  = lane & 31, h = lane >> 5;
    const int qt   = blockIdx.x, ks = blockIdx.y;

    // key range in 32-key units (288 total)
    const int base = 288 / KS, rem = 288 % KS;
    const int start = ks * base + (ks < rem ? ks : rem);
    const int cnt   = base + (ks < rem ? 1 : 0);

    // Q B-frags in registers (48 VGPR)
    const int qw = qt * 4 + w;
    hfrag qf[12];
    #pragma unroll
    for (int t = 0; t < 12; t++)
        qf[t] = *(const hfrag*)(const void*)(Qf + (((size_t)qw * 12 + t) * 64 + lane) * 8);

    facc16 O[6];
    #pragma unroll
    for (int cb = 0; cb < 6; cb++)
        #pragma unroll
        for (int j = 0; j < 16; j++) O[cb][j] = 0.f;
    float lsum = 0.f;

    // prologue: stage tiles 0 and 1 (6 loads each per wave)
    stage24(KV + (size_t)start * 12288,       (char*)&kv[0][0], w, lane);
    if (cnt > 1)
        stage24(KV + (size_t)(start + 1) * 12288, (char*)&kv[1][0], w, lane);

    const short* b0 = &kv[0][0];
    const short* b1 = &kv[1][0];
    const short* b2 = &kv[2][0];

    for (int kt = 0; kt < cnt; kt++) {
        // ---- tile boundary: counted wait (tile kt's batch landed) ----
        if (kt + 1 < cnt) { asm volatile("s_waitcnt vmcnt(6)" ::: "memory"); }
        else              { asm volatile("s_waitcnt vmcnt(0)" ::: "memory"); }
        __builtin_amdgcn_s_barrier();

        // stage tile kt+2 into b2 (its readers passed the previous barrier)
        if (kt + 2 < cnt)
            stage24(KV + (size_t)(start + kt + 2) * 12288, (char*)b2, w, lane);

        const short* kb = b0;

        // ---- QK cluster: loads run 4-8 MFMAs ahead of consumption ----
        hfrag k0 = KLD(0), k1 = KLD(1), k2 = KLD(2), k3 = KLD(3);
        hfrag k4 = KLD(4), k5 = KLD(5), k6 = KLD(6), k7 = KLD(7);
        facc16 S;
        #pragma unroll
        for (int j = 0; j < 16; j++) S[j] = 0.f;
        __builtin_amdgcn_s_setprio(1);
        QKM(k0, 0); QKM(k1, 1); QKM(k2, 2); QKM(k3, 3);
        hfrag k8 = KLD(8), k9 = KLD(9), k10 = KLD(10), k11 = KLD(11);
        QKM(k4, 4); QKM(k5, 5); QKM(k6, 6); QKM(k7, 7);
        bfrag v0 = VLD(0), v1 = VLD(1), v2 = VLD(2), v3 = VLD(3);
        QKM(k8, 8); QKM(k9, 9); QKM(k10, 10); QKM(k11, 11);
        __builtin_amdgcn_s_setprio(0);
        // S layout: key = (j&3)+8*(j>>2)+4*h (lane-local), q = l32

        // ---- P = 2^(S - M0L); tree-sum; pack (no cross-lane moves) ----
        float p[16];
        #pragma unroll
        for (int j = 0; j < 16; j++) p[j] = exp2_raw(S[j] - M0L);
        lsum += (((p[0]+p[1])+(p[2]+p[3]))+((p[4]+p[5])+(p[6]+p[7])))
              + (((p[8]+p[9])+(p[10]+p[11]))+((p[12]+p[13])+(p[14]+p[15])));
        int cp[8];
        #pragma unroll
        for (int a = 0; a < 8; a++) cp[a] = cvtpk_bf16(p[2 * a], p[2 * a + 1]);
        bfrag pf0 = __builtin_bit_cast(bfrag, (ifrag4){cp[0], cp[1], cp[2], cp[3]});
        bfrag pf1 = __builtin_bit_cast(bfrag, (ifrag4){cp[4], cp[5], cp[6], cp[7]});

        // ---- PV cluster (V rows pre-permuted; pf = cvt_pk words) ----
        bfrag v4 = VLD(4), v5 = VLD(5), v6 = VLD(6), v7 = VLD(7);
        __builtin_amdgcn_s_setprio(1);
        PVM(v0, 0, pf0); PVM(v1, 1, pf0); PVM(v2, 2, pf0); PVM(v3, 3, pf0);
        bfrag v8 = VLD(8), v9 = VLD(9), v10 = VLD(10), v11 = VLD(11);
        PVM(v4, 4, pf0); PVM(v5, 5, pf0);
        PVM(v6, 0, pf1); PVM(v7, 1, pf1);
        PVM(v8, 2, pf1); PVM(v9, 3, pf1); PVM(v10, 4, pf1); PVM(v11, 5, pf1);
        __builtin_amdgcn_s_setprio(0);

        // rotate triple buffer (wave-uniform pointer swap)
        const short* tmp = b0; b0 = b1; b1 = b2; b2 = tmp;
    }

    // ---- epilogue: Opart[ks][q][c] (bf16, unnormalized) + l per query ----
    const int q0 = qt * 128 + w * 32 + l32;
    short* row = Opart + ((size_t)ks * NQ + q0) * NC;
    #pragma unroll
    for (int cb = 0; cb < 6; cb++) {
        #pragma unroll
        for (int g = 0; g < 4; g++) {
            const int c0 = cb * 32 + 8 * g + 4 * h;
            sfrag4 s4;
            #pragma unroll
            for (int r = 0; r < 4; r++) s4[r] = f2bf(O[cb][4 * g + r]);
            *(sfrag4*)(void*)(row + c0) = s4;
        }
    }
    float lt = lsum + __shfl_xor(lsum, 32);
    if (h == 0) l_ws[(size_t)ks * NQ + q0] = lt;
}

// ---------------------------------------------------------------------------
// Combine: sum KS partials (common scale), normalize, transpose via LDS,
// fused epilogue out = refined*w5 + ctx.  288 blocks x 32 queries.
// ---------------------------------------------------------------------------
__global__ __launch_bounds__(256) void InterGate_combine(
    const short* __restrict__ Opart, const float* __restrict__ l_ws,
    const float* __restrict__ refined, const float* __restrict__ w5,
    float* __restrict__ out, int KS)
{
    __shared__ float ctx[32][193];
    __shared__ float sInv[32];
    const int qt = blockIdx.x, tid = threadIdx.x;

    if (tid < 32) {
        const int q = qt * 32 + tid;
        float L = 0.f;
        for (int ks = 0; ks < KS; ks++) L += l_ws[(size_t)ks * NQ + q];
        sInv[tid] = 1.f / L;
    }
    __syncthreads();

    for (int u = tid; u < 768; u += 256) {
        const int ql = u / 24, c0 = (u % 24) * 8;
        float acc[8] = {0.f, 0.f, 0.f, 0.f, 0.f, 0.f, 0.f, 0.f};
        for (int ks = 0; ks < KS; ks++) {
            bfrag pk = *(const bfrag*)(const void*)&Opart[((size_t)ks * NQ + qt * 32 + ql) * NC + c0];
            #pragma unroll
            for (int j = 0; j < 8; j++) acc[j] += bf2f(pk[j]);
        }
        const float inv = sInv[ql];
        #pragma unroll
        for (int j = 0; j < 8; j++) ctx[ql][c0 + j] = acc[j] * inv;
    }
    __syncthreads();

    for (int u = tid; u < 6144; u += 256) {
        const int c = u / 32, qx = u % 32;
        size_t o = (size_t)c * NQ + qt * 32 + qx;
        out[o] = refined[o] * w5[o] + ctx[qx][c];
    }
}

// ---------------------------------------------------------------------------
extern "C" void kernel_launch(void* const* d_in, const int* in_sizes, int n_in,
                              void* d_out, int out_size, void* d_ws, size_t ws_size,
                              hipStream_t stream)
{
    (void)in_sizes; (void)n_in; (void)out_size;
    const float* latent  = (const float*)d_in[0];
    const float* refined = (const float*)d_in[1];
    const float* w4      = (const float*)d_in[2];
    const float* w5      = (const float*)d_in[3];
    float* out = (float*)d_out;

    short* Qf = (short*)d_ws;
    short* KV = Qf + FR;                     // 2*FR shorts (K|V per 32-key group)
    const size_t basebytes = (size_t)3 * FR * 2;

    // KS=7 -> grid 504 (~2 blocks/CU, 72KB LDS each); fallbacks if ws small
    const int opts[4] = {7, 4, 2, 1};
    int KS = 0;
    for (int i = 0; i < 4; i++) {
        size_t need = basebytes + (size_t)opts[i] * ((size_t)NQ * NC * 2 + (size_t)NQ * 4);
        if (need <= ws_size) { KS = opts[i]; break; }
    }
    if (KS == 0) return;

    short* Opart = (short*)((char*)d_ws + basebytes);
    float* l_ws  = (float*)((char*)d_ws + basebytes + (size_t)KS * NQ * NC * 2);

    InterGate_prep<<<2592, 256, 0, stream>>>(latent, refined, w4, Qf, KV);
    dim3 fg(72, KS);
    InterGate_flash<<<fg, 256, 0, stream>>>(Qf, KV, Opart, l_ws, KS);
    InterGate_combine<<<288, 256, 0, stream>>>(Opart, l_ws, refined, w5, out, KS);
}

// Round 11
// 96.492 us; speedup vs baseline: 1.0319x; 1.0162x over previous
//
#include <hip/hip_runtime.h>
#include <stdint.h>

// InterGate: B=1, C=192, H=W=96.  Flash-attention formulation:
//   Q = (latent*w4)^T, K = refined^T, V = (latent*w4)^T   (all [9216, 192])
//   out = refined*w5 + (softmax(Q K^T) V)^T
// Round-11: r10 skeleton (4 waves x 32q, 32-key tiles, 3x24KB bufs, counted
// vmcnt(6), 2 blocks/CU) + three micro-levers against the measured ~92%
// phase serialization:
//   1. QK accumulator split into two 6-deep chains (Sa,Sb) -> dependent
//      MFMA latency halves; P = exp2(Sa+Sb)
//   2. -M0L folded into Sa's C-init (saves the 16 per-tile subtracts)
//   3. sched_group_barrier pins 1 ds_read : 1 MFMA interleave (T19)
//   * f16 single-term swapped QK, no-max softmax, permuted-V rows
//     (P B-frag = cvt_pk words, zero cross-lane moves)  [validated r3-r10]

#define NQ 9216
#define NC 192
#define FR 1769472      // 9216*192 elements per fragment array
#define LOG2E 1.4426950408889634f
#define M0L 36.06737602f   // 25 * log2(e)

typedef short    bfrag  __attribute__((ext_vector_type(8)));   // 8 bf16
typedef _Float16 hfrag  __attribute__((ext_vector_type(8)));   // 8 f16
typedef short    sfrag4 __attribute__((ext_vector_type(4)));   // 4 bf16 (8B)
typedef float    facc16 __attribute__((ext_vector_type(16)));  // 32x32 accum
typedef int      ifrag4 __attribute__((ext_vector_type(4)));

__device__ __forceinline__ short f2bf(float x) {
    uint32_t u = __builtin_bit_cast(uint32_t, x);
    u = (u + 0x7fffu + ((u >> 16) & 1u)) >> 16;
    return (short)u;
}
__device__ __forceinline__ float bf2f(short s) {
    uint32_t u = ((uint32_t)(uint16_t)s) << 16;
    return __builtin_bit_cast(float, u);
}
__device__ __forceinline__ int cvtpk_bf16(float lo, float hi) {
    int r;
    asm("v_cvt_pk_bf16_f32 %0, %1, %2" : "=v"(r) : "v"(lo), "v"(hi));
    return r;
}
__device__ __forceinline__ float exp2_raw(float x) {   // 2^x via v_exp_f32
    float r;
    asm("v_exp_f32 %0, %1" : "=v"(r) : "v"(x));
    return r;
}
__device__ __forceinline__ void gload_lds16(const void* g, void* l) {
    __builtin_amdgcn_global_load_lds(
        (__attribute__((address_space(1))) const void*)(uintptr_t)g,
        (__attribute__((address_space(3))) void*)(uint32_t)(uintptr_t)l,
        16, 0, 0);
}

// ---------------------------------------------------------------------------
// Prep: fragment-ordered arrays for 32x32x16 (l32=lane&31, h=lane>>5).
// Qf (f16, B-frag, pre-scaled by log2e):
//   [qw(288)][t(12)][lane][i8] = log2e * Q[qw*32+l32][t*16+h*8+i]
// KV per 32-key group g (12288 shorts = 24KB), 288 groups:
//  [0]    K (f16, A-frag): [t(12)][lane][i8] = K[g*32+l32][t*16+h*8+i]
//  [6144] V (bf16, A-frag of V^T, PERMUTED key rows matching S' C/D order):
//         [T(2)][cb(6)][lane][i8] = V[g*32+T*16+(i&3)+8*(i>>2)+4*h][cb*32+l32]
// ---------------------------------------------------------------------------
__global__ __launch_bounds__(256) void InterGate_prep(
    const float* __restrict__ latent, const float* __restrict__ refined,
    const float* __restrict__ w4,
    short* __restrict__ Qf, short* __restrict__ KV)
{
    const int wid  = blockIdx.x * 4 + (threadIdx.x >> 6);
    const int lane = threadIdx.x & 63;
    const int l32  = lane & 31, h = lane >> 5;

    if (wid < 3456) {                       // Q fragments (latent*w4*log2e), f16
        const int qw = wid / 12, t = wid % 12;
        const int q  = qw * 32 + l32;
        const int c0 = t * 16 + h * 8;
        hfrag hv;
        #pragma unroll
        for (int i = 0; i < 8; i++) {
            size_t idx = (size_t)(c0 + i) * NQ + q;
            hv[i] = (_Float16)(latent[idx] * w4[idx] * LOG2E);
        }
        *(hfrag*)(void*)(Qf + ((size_t)wid * 64 + lane) * 8) = hv;
    } else if (wid < 6912) {                // K fragments (refined), f16
        const int u = wid - 3456;           // u = g*12 + t
        const int g = u / 12, t = u % 12;
        const int key = g * 32 + l32;
        const int c0  = t * 16 + h * 8;
        hfrag hv;
        #pragma unroll
        for (int i = 0; i < 8; i++) {
            size_t idx = (size_t)(c0 + i) * NQ + key;
            hv[i] = (_Float16)refined[idx];
        }
        *(hfrag*)(void*)(KV + (size_t)g * 12288 + ((t * 64 + lane) * 8)) = hv;
    } else {                                // V fragments (latent*w4), bf16, permuted
        const int u = wid - 6912;           // u = g*12 + T*6 + cb
        const int g = u / 12, r = u % 12;
        const int T = r / 6, cb = r % 6;
        const int c  = cb * 32 + l32;
        const int k0 = g * 32 + T * 16 + 4 * h;
        bfrag bv;
        #pragma unroll
        for (int i = 0; i < 8; i++) {
            const int row = k0 + (i & 3) + 8 * (i >> 2);
            size_t idx = (size_t)c * NQ + row;
            bv[i] = f2bf(latent[idx] * w4[idx]);
        }
        *(bfrag*)(void*)(KV + (size_t)g * 12288 + 6144 + ((T * 6 + cb) * 64 + lane) * 8) = bv;
    }
}

// ---------------------------------------------------------------------------
// Flash: grid (72 q-tiles of 128, KS key-splits in 32-key units), 4 waves
// x 32 q, 72KB LDS/block -> 2 blocks/CU.  Triple-buffered 24KB K|V tiles,
// staged 2 ahead; split QK chains; SGB-pinned read/MFMA interleave.
// ---------------------------------------------------------------------------
__device__ __forceinline__ void stage24(const short* KVsrc, char* dstb,
                                        int w, int lane) {
    const char* src = (const char*)KVsrc + w * 6144 + lane * 16;
    char* dst = dstb + w * 6144;            // wave-uniform base (+lane*16 HW)
    #pragma unroll
    for (int j = 0; j < 6; j++) gload_lds16(src + j * 1024, dst + j * 1024);
}

#define KLD(n)  *(const hfrag*)(const void*)(kb + (n) * 512 + lane * 8)
#define VLD(n)  *(const bfrag*)(const void*)(kb + 6144 + (n) * 512 + lane * 8)
#define QKA(kf, t)  Sa = __builtin_amdgcn_mfma_f32_32x32x16_f16((kf), qf[t], Sa, 0, 0, 0)
#define QKB(kf, t)  Sb = __builtin_amdgcn_mfma_f32_32x32x16_f16((kf), qf[t], Sb, 0, 0, 0)
#define PVM(vf, cb, pf) O[cb] = __builtin_amdgcn_mfma_f32_32x32x16_bf16((vf), (pf), O[cb], 0, 0, 0)
#define SGB __builtin_amdgcn_sched_group_barrier

__global__ __launch_bounds__(256, 2) void InterGate_flash(
    const short* __restrict__ Qf, const short* __restrict__ KV,
    short* __restrict__ Opart, float* __restrict__ l_ws, int KS)
{
    __shared__ __align__(16) short kv[3][12288];   // 3 x 24KB: K(f16) | V(bf16)

    const int tid  = threadIdx.x;
    const int lane = tid & 63, w = tid >> 6;
    const int l32  = lane & 31, h = lane >> 5;
    const int qt   = blockIdx.x, ks = blockIdx.y;

    // key range in 32-key units (288 total)
    const int base = 288 / KS, rem = 288 % KS;
    const int start = ks * base + (ks < rem ? ks : rem);
    const int cnt   = base + (ks < rem ? 1 : 0);

    // Q B-frags in registers (48 VGPR)
    const int qw = qt * 4 + w;
    hfrag qf[12];
    #pragma unroll
    for (int t = 0; t < 12; t++)
        qf[t] = *(const hfrag*)(const void*)(Qf + (((size_t)qw * 12 + t) * 64 + lane) * 8);

    facc16 O[6];
    #pragma unroll
    for (int cb = 0; cb < 6; cb++)
        #pragma unroll
        for (int j = 0; j < 16; j++) O[cb][j] = 0.f;
    float lsum = 0.f;

    // prologue: stage tiles 0 and 1 (6 loads each per wave)
    stage24(KV + (size_t)start * 12288,       (char*)&kv[0][0], w, lane);
    if (cnt > 1)
        stage24(KV + (size_t)(start + 1) * 12288, (char*)&kv[1][0], w, lane);

    const short* b0 = &kv[0][0];
    const short* b1 = &kv[1][0];
    const short* b2 = &kv[2][0];

    for (int kt = 0; kt < cnt; kt++) {
        // ---- tile boundary: counted wait (tile kt's batch landed) ----
        if (kt + 1 < cnt) { asm volatile("s_waitcnt vmcnt(6)" ::: "memory"); }
        else              { asm volatile("s_waitcnt vmcnt(0)" ::: "memory"); }
        __builtin_amdgcn_s_barrier();

        // stage tile kt+2 into b2 (its readers passed the previous barrier)
        if (kt + 2 < cnt)
            stage24(KV + (size_t)(start + kt + 2) * 12288, (char*)b2, w, lane);

        const short* kb = b0;

        // ---- QK cluster: two 6-deep chains (Sa has -M0L folded in) ----
        hfrag k0 = KLD(0), k1 = KLD(1), k2 = KLD(2), k3 = KLD(3);
        facc16 Sa, Sb;
        #pragma unroll
        for (int j = 0; j < 16; j++) { Sa[j] = -M0L; Sb[j] = 0.f; }
        __builtin_amdgcn_s_setprio(1);
        hfrag k4  = KLD(4);  QKA(k0, 0);
        hfrag k5  = KLD(5);  QKB(k1, 1);
        hfrag k6  = KLD(6);  QKA(k2, 2);
        hfrag k7  = KLD(7);  QKB(k3, 3);
        hfrag k8  = KLD(8);  QKA(k4, 4);
        hfrag k9  = KLD(9);  QKB(k5, 5);
        hfrag k10 = KLD(10); QKA(k6, 6);
        hfrag k11 = KLD(11); QKB(k7, 7);
        bfrag v0  = VLD(0);  QKA(k8, 8);
        bfrag v1  = VLD(1);  QKB(k9, 9);
        bfrag v2  = VLD(2);  QKA(k10, 10);
        bfrag v3  = VLD(3);  QKB(k11, 11);
        __builtin_amdgcn_s_setprio(0);
        // S layout: key = (j&3)+8*(j>>2)+4*h (lane-local), q = l32

        // ---- P = 2^(Sa+Sb); tree-sum; pack (no cross-lane moves) ----
        float p[16];
        #pragma unroll
        for (int j = 0; j < 16; j++) p[j] = exp2_raw(Sa[j] + Sb[j]);
        lsum += (((p[0]+p[1])+(p[2]+p[3]))+((p[4]+p[5])+(p[6]+p[7])))
              + (((p[8]+p[9])+(p[10]+p[11]))+((p[12]+p[13])+(p[14]+p[15])));
        int cp[8];
        #pragma unroll
        for (int a = 0; a < 8; a++) cp[a] = cvtpk_bf16(p[2 * a], p[2 * a + 1]);
        bfrag pf0 = __builtin_bit_cast(bfrag, (ifrag4){cp[0], cp[1], cp[2], cp[3]});
        bfrag pf1 = __builtin_bit_cast(bfrag, (ifrag4){cp[4], cp[5], cp[6], cp[7]});

        // ---- PV cluster (V rows pre-permuted; pf = cvt_pk words) ----
        __builtin_amdgcn_s_setprio(1);
        bfrag v4  = VLD(4);  PVM(v0, 0, pf0);
        bfrag v5  = VLD(5);  PVM(v1, 1, pf0);
        bfrag v6  = VLD(6);  PVM(v2, 2, pf0);
        bfrag v7  = VLD(7);  PVM(v3, 3, pf0);
        bfrag v8  = VLD(8);  PVM(v4, 4, pf0);
        bfrag v9  = VLD(9);  PVM(v5, 5, pf0);
        bfrag v10 = VLD(10); PVM(v6, 0, pf1);
        bfrag v11 = VLD(11); PVM(v7, 1, pf1);
        PVM(v8, 2, pf1); PVM(v9, 3, pf1); PVM(v10, 4, pf1); PVM(v11, 5, pf1);
        __builtin_amdgcn_s_setprio(0);

        // ---- SGB pin: 4 reads, then 20x {1 read : 1 MFMA}, then 4 MFMA ----
        SGB(0x100, 4, 0);                      // k0..k3
        #pragma unroll
        for (int i = 0; i < 12; i++) { SGB(0x100, 1, 0); SGB(0x8, 1, 0); }
        #pragma unroll
        for (int i = 0; i < 8; i++)  { SGB(0x100, 1, 0); SGB(0x8, 1, 0); }
        SGB(0x8, 4, 0);                        // final PV MFMAs

        // rotate triple buffer (wave-uniform pointer swap)
        const short* tmp = b0; b0 = b1; b1 = b2; b2 = tmp;
    }

    // ---- epilogue: Opart[ks][q][c] (bf16, unnormalized) + l per query ----
    const int q0 = qt * 128 + w * 32 + l32;
    short* row = Opart + ((size_t)ks * NQ + q0) * NC;
    #pragma unroll
    for (int cb = 0; cb < 6; cb++) {
        #pragma unroll
        for (int g = 0; g < 4; g++) {
            const int c0 = cb * 32 + 8 * g + 4 * h;
            sfrag4 s4;
            #pragma unroll
            for (int r = 0; r < 4; r++) s4[r] = f2bf(O[cb][4 * g + r]);
            *(sfrag4*)(void*)(row + c0) = s4;
        }
    }
    float lt = lsum + __shfl_xor(lsum, 32);
    if (h == 0) l_ws[(size_t)ks * NQ + q0] = lt;
}

// ---------------------------------------------------------------------------
// Combine: sum KS partials (common scale), normalize, transpose via LDS,
// fused epilogue out = refined*w5 + ctx.  288 blocks x 32 queries.
// ---------------------------------------------------------------------------
__global__ __launch_bounds__(256) void InterGate_combine(
    const short* __restrict__ Opart, const float* __restrict__ l_ws,
    const float* __restrict__ refined, const float* __restrict__ w5,
    float* __restrict__ out, int KS)
{
    __shared__ float ctx[32][193];
    __shared__ float sInv[32];
    const int qt = blockIdx.x, tid = threadIdx.x;

    if (tid < 32) {
        const int q = qt * 32 + tid;
        float L = 0.f;
        for (int ks = 0; ks < KS; ks++) L += l_ws[(size_t)ks * NQ + q];
        sInv[tid] = 1.f / L;
    }
    __syncthreads();

    for (int u = tid; u < 768; u += 256) {
        const int ql = u / 24, c0 = (u % 24) * 8;
        float acc[8] = {0.f, 0.f, 0.f, 0.f, 0.f, 0.f, 0.f, 0.f};
        for (int ks = 0; ks < KS; ks++) {
            bfrag pk = *(const bfrag*)(const void*)&Opart[((size_t)ks * NQ + qt * 32 + ql) * NC + c0];
            #pragma unroll
            for (int j = 0; j < 8; j++) acc[j] += bf2f(pk[j]);
        }
        const float inv = sInv[ql];
        #pragma unroll
        for (int j = 0; j < 8; j++) ctx[ql][c0 + j] = acc[j] * inv;
    }
    __syncthreads();

    for (int u = tid; u < 6144; u += 256) {
        const int c = u / 32, qx = u % 32;
        size_t o = (size_t)c * NQ + qt * 32 + qx;
        out[o] = refined[o] * w5[o] + ctx[qx][c];
    }
}

// ---------------------------------------------------------------------------
extern "C" void kernel_launch(void* const* d_in, const int* in_sizes, int n_in,
                              void* d_out, int out_size, void* d_ws, size_t ws_size,
                              hipStream_t stream)
{
    (void)in_sizes; (void)n_in; (void)out_size;
    const float* latent  = (const float*)d_in[0];
    const float* refined = (const float*)d_in[1];
    const float* w4      = (const float*)d_in[2];
    const float* w5      = (const float*)d_in[3];
    float* out = (float*)d_out;

    short* Qf = (short*)d_ws;
    short* KV = Qf + FR;                     // 2*FR shorts (K|V per 32-key group)
    const size_t basebytes = (size_t)3 * FR * 2;

    // KS=7 -> grid 504 (~2 blocks/CU, 72KB LDS each); fallbacks if ws small
    const int opts[4] = {7, 4, 2, 1};
    int KS = 0;
    for (int i = 0; i < 4; i++) {
        size_t need = basebytes + (size_t)opts[i] * ((size_t)NQ * NC * 2 + (size_t)NQ * 4);
        if (need <= ws_size) { KS = opts[i]; break; }
    }
    if (KS == 0) return;

    short* Opart = (short*)((char*)d_ws + basebytes);
    float* l_ws  = (float*)((char*)d_ws + basebytes + (size_t)KS * NQ * NC * 2);

    InterGate_prep<<<2592, 256, 0, stream>>>(latent, refined, w4, Qf, KV);
    dim3 fg(72, KS);
    InterGate_flash<<<fg, 256, 0, stream>>>(Qf, KV, Opart, l_ws, KS);
    InterGate_combine<<<288, 256, 0, stream>>>(Opart, l_ws, refined, w5, out, KS);
}